// Round 17
// baseline (589.077 us; speedup 1.0000x reference)
//
#include <hip/hip_runtime.h>
#include <hip/hip_bf16.h>

typedef unsigned short u16;
typedef unsigned int   u32;

#define MP     3328          // padded token rows (26*128 = 13*256)
#define MREAL  3140          // B*N = 4*785
#define DIMC   1024
#define H3C    3072
#define HIDC   4096
#define NKV    785
#define SLEN   896           // padded V^T row length (7*128)

typedef __bf16 bf16x8 __attribute__((ext_vector_type(8)));
typedef float  f32x4  __attribute__((ext_vector_type(4)));

#define MFMA(d,a,b) (d) = __builtin_amdgcn_mfma_f32_16x16x32_bf16((a),(b),(d),0,0,0)

__device__ __forceinline__ u16 f2bf(float f){
  u32 u = __builtin_bit_cast(u32, f);
  return (u16)((u + 0x7fffu + ((u >> 16) & 1u)) >> 16);
}
__device__ __forceinline__ float bf2f(u16 h){
  return __builtin_bit_cast(float, (u32)h << 16);
}
__device__ __forceinline__ void gload16(const u16* g, u16* l){
  __builtin_amdgcn_global_load_lds(
      (const __attribute__((address_space(1))) void*)g,
      (__attribute__((address_space(3))) void*)l, 16, 0, 0);
}
__device__ __forceinline__ float wsum(float v){
  #pragma unroll
  for (int o = 32; o >= 1; o >>= 1) v += __shfl_xor(v, o);
  return v;
}

// ---------------- fp32 -> bf16 weight conversion (pairs fused) --------------
__global__ __launch_bounds__(256) void cvt2_k(
    const float* __restrict__ in0, u16* __restrict__ out0, int n0,
    const float* __restrict__ in1, u16* __restrict__ out1, int n1)
{
  int i = (blockIdx.x * 256 + threadIdx.x) * 4;
  const float* src; u16* dst;
  if (i < n0){ src = in0 + i; dst = out0 + i; }
  else { int j = i - n0; if (j >= n1) return; src = in1 + j; dst = out1 + j; }
  float4 v = *(const float4*)src;
  ushort4 o4;
  o4.x = f2bf(v.x); o4.y = f2bf(v.y); o4.z = f2bf(v.z); o4.w = f2bf(v.w);
  *(ushort4*)dst = o4;
}

// ---------------- LayerNorm + JVP (fp32 in -> bf16 out, zero pad rows) -----
__global__ __launch_bounds__(256) void ln_jvp_k(
    const float* __restrict__ x, const float* __restrict__ xj,
    const float* __restrict__ w, const float* __restrict__ b,
    const float* __restrict__ lw, const float* __restrict__ lb,
    u16* __restrict__ out, u16* __restrict__ outj)
{
  const int row = blockIdx.x, t = threadIdx.x;
  const size_t ro = (size_t)row * DIMC;
  if (row >= MREAL){
    for (int i = t; i < DIMC; i += 256){ out[ro+i] = 0; outj[ro+i] = 0; }
    return;
  }
  const float4 v  = ((const float4*)(x  + ro))[t];
  const float4 vj = ((const float4*)(xj + ro))[t];
  float sx  = v.x+v.y+v.z+v.w;
  float sxx = v.x*v.x+v.y*v.y+v.z*v.z+v.w*v.w;
  float sj  = vj.x+vj.y+vj.z+vj.w;
  float sxj = v.x*vj.x+v.y*vj.y+v.z*vj.z+v.w*vj.w;
  __shared__ __attribute__((aligned(64))) float red[4][4];
  sx = wsum(sx); sxx = wsum(sxx); sj = wsum(sj); sxj = wsum(sxj);
  const int wid = t>>6, lane = t&63;
  if (lane == 0){ red[wid][0]=sx; red[wid][1]=sxx; red[wid][2]=sj; red[wid][3]=sxj; }
  __syncthreads();
  sx  = red[0][0]+red[1][0]+red[2][0]+red[3][0];
  sxx = red[0][1]+red[1][1]+red[2][1]+red[3][1];
  sj  = red[0][2]+red[1][2]+red[2][2]+red[3][2];
  sxj = red[0][3]+red[1][3]+red[2][3]+red[3][3];
  const float inv  = 1.0f/1024.0f;
  const float mean = sx*inv, meanj = sj*inv;
  const float var  = sxx*inv - mean*mean;
  const float cov  = sxj*inv - mean*meanj;       // mean(xc*xjc)
  const float rstd = rsqrtf(var + 1e-5f);
  const float r3   = rstd*rstd*rstd;
  const float4 wv  = ((const float4*)w)[t];
  const float4 bv  = ((const float4*)b)[t];
  const float4 lwv = ((const float4*)lw)[t];
  const float4 lbv = ((const float4*)lb)[t];
  const float xs[4]  = {v.x,v.y,v.z,v.w},   xjs[4] = {vj.x,vj.y,vj.z,vj.w};
  const float wss[4] = {wv.x,wv.y,wv.z,wv.w}, bs[4] = {bv.x,bv.y,bv.z,bv.w};
  const float lws[4] = {lwv.x,lwv.y,lwv.z,lwv.w}, lbs[4] = {lbv.x,lbv.y,lbv.z,lbv.w};
  const int i0 = t*4;
  #pragma unroll
  for (int e = 0; e < 4; e++){
    const float xc = xs[e]-mean, xjc = xjs[e]-meanj;
    const float xhat = xc*rstd;
    const float cc = xjc*rstd - xc*cov*r3;       // == (1/std^2)(a - bterm)
    out [ro+i0+e] = f2bf(xhat*wss[e] + bs[e]);
    outj[ro+i0+e] = f2bf(xhat*lws[e] + lbs[e] + cc*wss[e]);
  }
}

// ======== W64 JVP GEMM: BM=256 BN=64 BK=32, 4 waves, 2-buf, 2 blk/CU ========
// Combines the two proven properties: BM=256 (B-reuse: halves per-M-stripe
// B re-stream — r15 lesson) and 2 blocks/CU TLP (the r14 +10us mechanism
// that put fc2 at 26.8% MfmaUtil). Per buf: A pair 32KB + B pair 8KB = 40KB;
// 2-buf = 80KB -> exactly 2 blocks/CU. Counted vmcnt(10) (10 loads/thread/
// K-step), post-compute barrier guards WAR on buffer reuse. XOR-swizzle +
// XCD swizzle (XCD r always gets B-cols x==r mod 8 -> per-XCD B slice 3-4MB
// stays L2-resident across M-stripes). Waves stack in M: wave tile 64x64.
// EPI 0: bf16 (qkv). EPI 2: GELU-JVP bf16 (fc1).
template<int EPI>
__global__ __launch_bounds__(256) void gemm_jvp_w64_k(
    const u16* __restrict__ A, const u16* __restrict__ Aj, int lda,
    const u16* __restrict__ B, const u16* __restrict__ Bj, int K,
    const float* __restrict__ bias, const float* __restrict__ biasj,
    void* __restrict__ Yv, void* __restrict__ Yjv, int ldy)
{
  // [buf]: A[0,8192) Aj[8192,16384) B[16384,18432) Bj[18432,20480) u16
  __shared__ __attribute__((aligned(128))) u16 lds[2][20480];
  const int tid = threadIdx.x, wid = tid>>6, lane = tid&63;
  const int l4 = lane>>4, l15 = lane&15;
  const int ord = blockIdx.y * gridDim.x + blockIdx.x;
  const int cpx = (gridDim.x * gridDim.y) >> 3;
  const int nbk = (ord & 7) * cpx + (ord >> 3);
  const int m0 = (nbk / gridDim.x) * 256;
  const int n0 = (nbk % gridDim.x) * 64;
  f32x4 accY[4][4], accJ[4][4];
  #pragma unroll
  for (int i = 0; i < 4; i++)
    #pragma unroll
    for (int j = 0; j < 4; j++){
      accY[i][j] = (f32x4){0.f,0.f,0.f,0.f};
      accJ[i][j] = (f32x4){0.f,0.f,0.f,0.f};
    }
  // A staging: 4 granules/thread (16KB per operand); pre-swizzled source
  const u16* srcA [4];
  const u16* srcAj[4];
  #pragma unroll
  for (int g = 0; g < 4; g++){
    const int bo = (g*256 + tid)*16;
    const int sb = bo ^ (((bo>>7)&7)<<4);
    const int r = sb>>6, c = (sb&63)>>1;
    srcA [g] = A  + (size_t)(m0+r)*lda + c;
    srcAj[g] = Aj + (size_t)(m0+r)*lda + c;
  }
  // B staging: 1 granule/thread (4KB per operand)
  const int boB = tid*16;
  const int sbB = boB ^ (((boB>>7)&7)<<4);
  const int rB = sbB>>6, cB = (sbB&63)>>1;
  const u16* srcB  = B  + (size_t)(n0+rB)*K + cB;
  const u16* srcBj = Bj + (size_t)(n0+rB)*K + cB;
  // swizzled fragment byte offsets
  int aoff[4], boff[4];
  #pragma unroll
  for (int i = 0; i < 4; i++){
    int ab_ = (wid*64 + i*16 + l15)*64 + l4*16;
    aoff[i] = ab_ ^ (((ab_>>7)&7)<<4);
    int bb_ = (i*16 + l15)*64 + l4*16;
    boff[i] = bb_ ^ (((bb_>>7)&7)<<4);
  }
  auto STAGE = [&](int buf, int t){
    const int k0 = t<<5;
    u16* Lb = &lds[buf][0];
    #pragma unroll
    for (int g = 0; g < 4; g++){
      gload16(srcA [g]+k0, Lb + (g*256+tid)*8);
      gload16(srcAj[g]+k0, Lb + 8192 + (g*256+tid)*8);
    }
    gload16(srcB +k0, Lb + 16384 + tid*8);
    gload16(srcBj+k0, Lb + 18432 + tid*8);
  };
  const int nt = K >> 5;
  STAGE(0, 0);
  STAGE(1, 1);
  for (int t = 0; t < nt; t++){
    if (t + 1 < nt) asm volatile("s_waitcnt vmcnt(10)" ::: "memory");
    else            asm volatile("s_waitcnt vmcnt(0)"  ::: "memory");
    __builtin_amdgcn_s_barrier();
    const char* Lb = (const char*)&lds[t&1][0];
    bf16x8 af[4], ajf[4], bbf[4], bjf[4];
    #pragma unroll
    for (int i = 0; i < 4; i++){
      af[i]  = *(const bf16x8*)(Lb + aoff[i]);
      ajf[i] = *(const bf16x8*)(Lb + 16384 + aoff[i]);
      bbf[i] = *(const bf16x8*)(Lb + 32768 + boff[i]);
      bjf[i] = *(const bf16x8*)(Lb + 36864 + boff[i]);
    }
    __builtin_amdgcn_s_setprio(1);
    #pragma unroll
    for (int i = 0; i < 4; i++)
      #pragma unroll
      for (int j = 0; j < 4; j++){
        MFMA(accY[i][j], af[i],  bbf[j]);
        MFMA(accJ[i][j], ajf[i], bbf[j]);
        MFMA(accJ[i][j], af[i],  bjf[j]);
      }
    __builtin_amdgcn_s_setprio(0);
    __builtin_amdgcn_s_barrier();          // all waves done reading buf[t&1]
    if (t + 2 < nt) STAGE(t&1, t+2);       // refill; flies across next wait
  }
  const int mb = m0 + wid*64 + (l4<<2);
  const int nb = n0 + l15;
  #pragma unroll
  for (int i = 0; i < 4; i++)
    #pragma unroll
    for (int j = 0; j < 4; j++)
      #pragma unroll
      for (int r = 0; r < 4; r++){
        const int m = mb + i*16 + r, n = nb + j*16;
        float y = accY[i][j][r], yj = accJ[i][j][r];
        if (EPI == 0){
          ((u16*)Yv )[(size_t)m*ldy+n] = f2bf(y);
          ((u16*)Yjv)[(size_t)m*ldy+n] = f2bf(yj);
        } else {
          y  += bias[n];
          yj += biasj[n];
          const float ge  = 0.5f*y*(1.0f + erff(y*0.70710678118654752f));
          const float pdf = __expf(-0.5f*y*y)*0.3989422804014327f;
          const float gj  = yj*(ge/(y + 1e-8f) + y*pdf);
          ((u16*)Yv )[(size_t)m*ldy+n] = f2bf(ge);
          ((u16*)Yjv)[(size_t)m*ldy+n] = f2bf(gj);
        }
      }
}

// ---------------- 128x128 JVP GEMM, 2-buffer counted-vmcnt ------------------
// Proven best for K=4096/narrow-N (fc2) and proj: 2-buffer LDS (64KB) ->
// 2 blocks/CU (8 waves TLP), counted vmcnt(8), post-compute barrier guards
// WAR on buffer reuse. XOR-swizzle + XCD swizzle.
template<int EPI>
__global__ __launch_bounds__(256) void gemm_jvp_k(
    const u16* __restrict__ A, const u16* __restrict__ Aj, int lda,
    const u16* __restrict__ B, const u16* __restrict__ Bj, int K,
    const float* __restrict__ bias, const float* __restrict__ biasj,
    const float* __restrict__ res, const float* __restrict__ resj,
    void* __restrict__ Yv, void* __restrict__ Yjv, int ldy, int mwrite)
{
  // [buf][tile: A,Aj,B,Bj][128x32 bf16] = 64 KB total
  __shared__ __attribute__((aligned(128))) u16 lds[2][4][128*32];
  const int tid = threadIdx.x, wid = tid>>6, lane = tid&63;
  const int ord = blockIdx.y * gridDim.x + blockIdx.x;
  const int cpx = (gridDim.x * gridDim.y) >> 3;
  const int nbk = (ord & 7) * cpx + (ord >> 3);
  const int m0 = (nbk / gridDim.x) * 128;
  const int n0 = (nbk % gridDim.x) * 128;
  f32x4 accY[4][4], accJ[4][4];
  #pragma unroll
  for (int i = 0; i < 4; i++)
    #pragma unroll
    for (int j = 0; j < 4; j++){
      accY[i][j] = (f32x4){0.f,0.f,0.f,0.f};
      accJ[i][j] = (f32x4){0.f,0.f,0.f,0.f};
    }
  const int bo0 = wid*1024 + lane*16;     // staging byte offset, round 0
  const int bo1 = bo0 + 4096;             // round 1
  const int sb0 = bo0 ^ (((bo0>>7)&7)<<4);
  const int sb1 = bo1 ^ (((bo1>>7)&7)<<4);
  const int r0 = sb0>>6, c0 = (sb0&63)>>1;
  const int r1 = sb1>>6, c1 = (sb1&63)>>1;
  const u16* A0  = A  + (size_t)(m0+r0)*lda + c0;
  const u16* A1  = A  + (size_t)(m0+r1)*lda + c1;
  const u16* Aj0 = Aj + (size_t)(m0+r0)*lda + c0;
  const u16* Aj1 = Aj + (size_t)(m0+r1)*lda + c1;
  const u16* B0  = B  + (size_t)(n0+r0)*K + c0;
  const u16* B1  = B  + (size_t)(n0+r1)*K + c1;
  const u16* Bj0 = Bj + (size_t)(n0+r0)*K + c0;
  const u16* Bj1 = Bj + (size_t)(n0+r1)*K + c1;
  const int kq = (lane>>4)<<3;
  const int ar = (wid>>1)*64 + (lane&15);
  const int bc = (wid&1)*64 + (lane&15);
  int aoff[4], boff[4];
  #pragma unroll
  for (int i = 0; i < 4; i++){
    int ab_ = (ar+i*16)*64 + (kq<<1);
    aoff[i] = ab_ ^ (((ab_>>7)&7)<<4);
    int bb_ = (bc+i*16)*64 + (kq<<1);
    boff[i] = bb_ ^ (((bb_>>7)&7)<<4);
  }
  auto STAGE = [&](int buf, int t){
    const int k0 = t<<5;
    u16* p0 = &lds[buf][0][0];
    gload16(A0 +k0, p0+(bo0>>1)); gload16(A1 +k0, p0+(bo1>>1));
    u16* p1 = &lds[buf][1][0];
    gload16(Aj0+k0, p1+(bo0>>1)); gload16(Aj1+k0, p1+(bo1>>1));
    u16* p2 = &lds[buf][2][0];
    gload16(B0 +k0, p2+(bo0>>1)); gload16(B1 +k0, p2+(bo1>>1));
    u16* p3 = &lds[buf][3][0];
    gload16(Bj0+k0, p3+(bo0>>1)); gload16(Bj1+k0, p3+(bo1>>1));
  };
  const int nt = K >> 5;
  STAGE(0, 0);
  STAGE(1, 1);
  for (int t = 0; t < nt; t++){
    if (t + 1 < nt) asm volatile("s_waitcnt vmcnt(8)" ::: "memory");
    else            asm volatile("s_waitcnt vmcnt(0)" ::: "memory");
    __builtin_amdgcn_s_barrier();
    const char* lAb  = (const char*)&lds[t&1][0][0];
    const char* lAjb = (const char*)&lds[t&1][1][0];
    const char* lBb  = (const char*)&lds[t&1][2][0];
    const char* lBjb = (const char*)&lds[t&1][3][0];
    bf16x8 af[4], ajf[4], bbf[4], bjf[4];
    #pragma unroll
    for (int i = 0; i < 4; i++){
      af[i]  = *(const bf16x8*)(lAb  + aoff[i]);
      ajf[i] = *(const bf16x8*)(lAjb + aoff[i]);
      bbf[i] = *(const bf16x8*)(lBb  + boff[i]);
      bjf[i] = *(const bf16x8*)(lBjb + boff[i]);
    }
    __builtin_amdgcn_s_setprio(1);
    #pragma unroll
    for (int i = 0; i < 4; i++)
      #pragma unroll
      for (int j = 0; j < 4; j++){
        MFMA(accY[i][j], af[i],  bbf[j]);
        MFMA(accJ[i][j], ajf[i], bbf[j]);
        MFMA(accJ[i][j], af[i],  bjf[j]);
      }
    __builtin_amdgcn_s_setprio(0);
    __builtin_amdgcn_s_barrier();          // all waves done reading buf[t&1]
    if (t + 2 < nt) STAGE(t&1, t+2);       // refill; flies across next wait
  }
  const int mb = m0 + (wid>>1)*64 + ((lane>>4)<<2);
  const int nb = n0 + (wid&1)*64 + (lane&15);
  #pragma unroll
  for (int i = 0; i < 4; i++)
    #pragma unroll
    for (int j = 0; j < 4; j++)
      #pragma unroll
      for (int r = 0; r < 4; r++){
        const int m = mb + i*16 + r, n = nb + j*16;
        float y = accY[i][j][r], yj = accJ[i][j][r];
        if (EPI == 0){
          ((u16*)Yv )[(size_t)m*ldy+n] = f2bf(y);
          ((u16*)Yjv)[(size_t)m*ldy+n] = f2bf(yj);
        } else if (EPI == 1){
          if (m < mwrite){
            y  += bias[n]  + res [(size_t)m*ldy+n];
            yj += biasj[n] + resj[(size_t)m*ldy+n];
            ((float*)Yv )[(size_t)m*ldy+n] = y;
            ((float*)Yjv)[(size_t)m*ldy+n] = yj;
          }
        } else {
          y  += bias[n];
          yj += biasj[n];
          const float ge  = 0.5f*y*(1.0f + erff(y*0.70710678118654752f));
          const float pdf = __expf(-0.5f*y*y)*0.3989422804014327f;
          const float gj  = yj*(ge/(y + 1e-8f) + y*pdf);
          ((u16*)Yv )[(size_t)m*ldy+n] = f2bf(ge);
          ((u16*)Yjv)[(size_t)m*ldy+n] = f2bf(gj);
        }
      }
}

// ---------------- V transpose: vT[bh][d][kv] (zero-padded kv>=785) ----------
__global__ __launch_bounds__(256) void transpose_v_k(
    const u16* __restrict__ qkvb, const u16* __restrict__ qkvjb,
    u16* __restrict__ vT, u16* __restrict__ vjT)
{
  __shared__ __attribute__((aligned(64))) u16 tl[64][80];
  __shared__ __attribute__((aligned(64))) u16 tlj[64][80];
  const int kt = blockIdx.x, bh = blockIdx.y;
  const int b = bh>>4, h = bh&15;
  const int t = threadIdx.x;
  const int kv = t>>2, dd = (t&3)*16;
  const int kvg = kt*64 + kv;
  if (kvg < NKV){
    const u16* s0 = qkvb  + (size_t)(b*NKV+kvg)*H3C + 2048 + h*64 + dd;
    const u16* s1 = qkvjb + (size_t)(b*NKV+kvg)*H3C + 2048 + h*64 + dd;
    *(uint4*)&tl [kv][dd]   = *(const uint4*)s0;
    *(uint4*)&tl [kv][dd+8] = *(const uint4*)(s0+8);
    *(uint4*)&tlj[kv][dd]   = *(const uint4*)s1;
    *(uint4*)&tlj[kv][dd+8] = *(const uint4*)(s1+8);
  } else {
    uint4 z = {0,0,0,0};
    *(uint4*)&tl [kv][dd] = z; *(uint4*)&tl [kv][dd+8] = z;
    *(uint4*)&tlj[kv][dd] = z; *(uint4*)&tlj[kv][dd+8] = z;
  }
  __syncthreads();
  const int d = t>>2, kc = (t&3)*16;
  u16* d0 = vT  + ((size_t)bh*64 + d)*SLEN + kt*64 + kc;
  u16* d1 = vjT + ((size_t)bh*64 + d)*SLEN + kt*64 + kc;
  #pragma unroll
  for (int e = 0; e < 16; e++){ d0[e] = tl[kc+e][d]; d1[e] = tlj[kc+e][d]; }
}

// ---------------- fused flash-style JVP attention ---------------------------
// K/Kj double-buffered, V single-buffered; counted vmcnt(4); l/g reductions
// deferred to epilogue; defer-max (skip rescale unless row max grew > 4).
// LDS = 80 KB -> 2 blocks/CU.
__global__ __launch_bounds__(256) void flash_attn_jvp_k(
    const u16* __restrict__ qkvb, const u16* __restrict__ qkvjb,
    const u16* __restrict__ vT, const u16* __restrict__ vjT,
    u16* __restrict__ o, u16* __restrict__ oj)
{
  __shared__ __attribute__((aligned(128))) u16 lK  [2][64*64];
  __shared__ __attribute__((aligned(128))) u16 lKj [2][64*64];
  __shared__ __attribute__((aligned(128))) u16 lvT [64*64];
  __shared__ __attribute__((aligned(128))) u16 lvjT[64*64];
  __shared__ __attribute__((aligned(128))) u16 pl  [128*64];
  __shared__ __attribute__((aligned(128))) u16 pdl [128*64];
  const int tid = threadIdx.x, wid = tid>>6, lane = tid&63;
  const int l4 = lane>>4, l15 = lane&15;
  const int qt = blockIdx.x, bh = blockIdx.y, b = bh>>4, h = bh&15;

  bf16x8 qf[2][2], qjf[2][2];
  {
    const size_t qrb = (size_t)b*NKV + qt*128 + wid*32;
    #pragma unroll
    for (int i = 0; i < 2; i++){
      const size_t ro = (qrb + i*16 + l15)*H3C + h*64;
      #pragma unroll
      for (int ks = 0; ks < 2; ks++){
        qf [i][ks] = *(const bf16x8*)(qkvb  + ro + ks*32 + l4*8);
        qjf[i][ks] = *(const bf16x8*)(qkvjb + ro + ks*32 + l4*8);
      }
    }
  }
  float m_st[2][4], l_pt[2][4], g_pt[2][4];
  f32x4 PO[2][4], PTJ[2][4];
  #pragma unroll
  for (int i = 0; i < 2; i++)
    #pragma unroll
    for (int r = 0; r < 4; r++){
      m_st[i][r] = -1e30f; l_pt[i][r] = 0.f; g_pt[i][r] = 0.f;
    }
  #pragma unroll
  for (int i = 0; i < 2; i++)
    #pragma unroll
    for (int j = 0; j < 4; j++){
      PO[i][j] = (f32x4){0.f,0.f,0.f,0.f};
      PTJ[i][j] = (f32x4){0.f,0.f,0.f,0.f};
    }
  char* plb  = (char*)pl;
  char* pdlb = (char*)pdl;
  const char* lvTb  = (const char*)lvT;
  const char* lvjTb = (const char*)lvjT;

  const int g0 = tid, g1 = 256 + tid;
  const int row0 = g0>>3, cs0 = (g0&7) ^ (row0&7);
  const int row1 = g1>>3, cs1 = (g1&7) ^ (row1&7);
  auto stageK = [&](int buf, int t){
    const size_t k0 = (size_t)(b*NKV + t*64 + row0)*H3C + 1024 + h*64 + cs0*8;
    const size_t k1 = (size_t)(b*NKV + t*64 + row1)*H3C + 1024 + h*64 + cs1*8;
    gload16(qkvb  + k0, &lK [buf][0] + g0*8);
    gload16(qkvjb + k0, &lKj[buf][0] + g0*8);
    gload16(qkvb  + k1, &lK [buf][0] + g1*8);
    gload16(qkvjb + k1, &lKj[buf][0] + g1*8);
  };
  auto stageV = [&](int t){
    const size_t v0 = ((size_t)bh*64 + row0)*SLEN + t*64 + cs0*8;
    const size_t v1 = ((size_t)bh*64 + row1)*SLEN + t*64 + cs1*8;
    gload16(vT  + v0, lvT  + g0*8);
    gload16(vjT + v0, lvjT + g0*8);
    gload16(vT  + v1, lvT  + g1*8);
    gload16(vjT + v1, lvjT + g1*8);
  };

  stageK(0, 0);
  stageV(0);
  for (int t = 0; t < 13; t++){
    asm volatile("s_waitcnt vmcnt(4)" ::: "memory");   // K(t) complete
    __builtin_amdgcn_s_barrier();
    const char* lKb  = (const char*)&lK [t&1][0];
    const char* lKjb = (const char*)&lKj[t&1][0];

    #pragma unroll
    for (int i = 0; i < 2; i++){
      f32x4 s[4], dm[4];
      #pragma unroll
      for (int j = 0; j < 4; j++){
        s[j] = (f32x4){0.f,0.f,0.f,0.f};
        dm[j] = (f32x4){0.f,0.f,0.f,0.f};
      }
      #pragma unroll
      for (int ks = 0; ks < 2; ks++){
        #pragma unroll
        for (int j = 0; j < 4; j++){
          const int row = j*16 + l15;
          const int byt = (row*128 + ks*64 + l4*16) ^ ((row&7)<<4);
          const bf16x8 kf  = *(const bf16x8*)(lKb  + byt);
          const bf16x8 kjf = *(const bf16x8*)(lKjb + byt);
          MFMA(s[j],  qf[i][ks],  kf);
          MFMA(dm[j], qjf[i][ks], kf);
          MFMA(dm[j], qf[i][ks],  kjf);
        }
      }
      float tm[4] = {-1e30f,-1e30f,-1e30f,-1e30f};
      #pragma unroll
      for (int j = 0; j < 4; j++){
        const int colg = t*64 + j*16 + l15;
        #pragma unroll
        for (int r = 0; r < 4; r++){
          float sv = s[j][r]*0.125f;
          if (colg >= NKV) sv = -1e30f;
          s[j][r] = sv;
          dm[j][r] *= 0.125f;
          tm[r] = fmaxf(tm[r], sv);
        }
      }
      float vmax[4];
      bool need = false;
      #pragma unroll
      for (int r = 0; r < 4; r++){
        float v = tm[r];
        v = fmaxf(v, __shfl_xor(v, 1));
        v = fmaxf(v, __shfl_xor(v, 2));
        v = fmaxf(v, __shfl_xor(v, 4));
        v = fmaxf(v, __shfl_xor(v, 8));
        vmax[r] = v;
        need = need || (v > m_st[i][r] + 4.0f);
      }
      if (__any(need)){
        #pragma unroll
        for (int r = 0; r < 4; r++){
          const float nm = fmaxf(m_st[i][r], vmax[r]);
          const float sc = __expf(m_st[i][r] - nm);
          m_st[i][r] = nm;
          l_pt[i][r] *= sc;
          g_pt[i][r] *= sc;
          #pragma unroll
          for (int j = 0; j < 4; j++){ PO[i][j][r] *= sc; PTJ[i][j][r] *= sc; }
        }
      }
      #pragma unroll
      for (int j = 0; j < 4; j++){
        const int col = j*16 + l15;
        #pragma unroll
        for (int r = 0; r < 4; r++){
          const float p  = __expf(s[j][r] - m_st[i][r]);
          const float pd = p * dm[j][r];
          l_pt[i][r] += p;
          g_pt[i][r] += pd;
          const int row = wid*32 + i*16 + l4*4 + r;
          const int byt = (row*128 + col*2) ^ ((row&7)<<4);
          *(u16*)(plb  + byt) = f2bf(p);
          *(u16*)(pdlb + byt) = f2bf(pd);
        }
      }
    }

    if (t + 1 < 13) stageK((t+1)&1, t+1);
    if (t + 1 < 13) asm volatile("s_waitcnt vmcnt(4)" ::: "memory");
    else            asm volatile("s_waitcnt vmcnt(0)" ::: "memory");
    __builtin_amdgcn_s_barrier();

    #pragma unroll
    for (int ks = 0; ks < 2; ks++){
      bf16x8 pa[2], pda[2];
      #pragma unroll
      for (int i = 0; i < 2; i++){
        const int row = wid*32 + i*16 + l15;
        const int byt = (row*128 + ks*64 + l4*16) ^ ((row&7)<<4);
        pa[i]  = *(const bf16x8*)(plb  + byt);
        pda[i] = *(const bf16x8*)(pdlb + byt);
      }
      #pragma unroll
      for (int j = 0; j < 4; j++){
        const int row = j*16 + l15;
        const int byt = (row*128 + ks*64 + l4*16) ^ ((row&7)<<4);
        const bf16x8 vb  = *(const bf16x8*)(lvTb  + byt);
        const bf16x8 vjb = *(const bf16x8*)(lvjTb + byt);
        #pragma unroll
        for (int i = 0; i < 2; i++){
          MFMA(PO[i][j],  pa[i],  vb);
          MFMA(PTJ[i][j], pda[i], vb);
          MFMA(PTJ[i][j], pa[i],  vjb);
        }
      }
    }
    __builtin_amdgcn_s_barrier();
    if (t + 1 < 13) stageV(t+1);
  }

  #pragma unroll
  for (int i = 0; i < 2; i++)
    #pragma unroll
    for (int r = 0; r < 4; r++){
      float lv = l_pt[i][r], gv = g_pt[i][r];
      lv += __shfl_xor(lv, 1); gv += __shfl_xor(gv, 1);
      lv += __shfl_xor(lv, 2); gv += __shfl_xor(gv, 2);
      lv += __shfl_xor(lv, 4); gv += __shfl_xor(gv, 4);
      lv += __shfl_xor(lv, 8); gv += __shfl_xor(gv, 8);
      const int ql = qt*128 + wid*32 + i*16 + l4*4 + r;
      if (ql < NKV){
        const float rl = 1.0f / lv;
        const float gg = gv * rl;
        #pragma unroll
        for (int j = 0; j < 4; j++){
          const size_t oo = ((size_t)b*NKV + ql)*DIMC + h*64 + j*16 + l15;
          const float po = PO[i][j][r] * rl;
          o [oo] = f2bf(po);
          oj[oo] = f2bf(PTJ[i][j][r]*rl - gg*po);
        }
      }
    }
}

// ---------------------------------------------------------------------------
extern "C" void kernel_launch(void* const* d_in, const int* in_sizes, int n_in,
                              void* d_out, int out_size, void* d_ws, size_t ws_size,
                              hipStream_t stream)
{
  (void)in_sizes; (void)n_in; (void)out_size;
  const float* input   = (const float*)d_in[0];
  const float* inputj  = (const float*)d_in[1];
  const float* n1_w    = (const float*)d_in[2];
  const float* n1_b    = (const float*)d_in[3];
  const float* n1_lw   = (const float*)d_in[4];
  const float* n1_lb   = (const float*)d_in[5];
  const float* qkv_w   = (const float*)d_in[6];
  const float* qkv_lw  = (const float*)d_in[7];
  const float* proj_w  = (const float*)d_in[8];
  const float* proj_b  = (const float*)d_in[9];
  const float* proj_lw = (const float*)d_in[10];
  const float* proj_lb = (const float*)d_in[11];
  const float* n2_w    = (const float*)d_in[12];
  const float* n2_b    = (const float*)d_in[13];
  const float* n2_lw   = (const float*)d_in[14];
  const float* n2_lb   = (const float*)d_in[15];
  const float* fc1_w   = (const float*)d_in[16];
  const float* fc1_b   = (const float*)d_in[17];
  const float* fc1_lw  = (const float*)d_in[18];
  const float* fc1_lb  = (const float*)d_in[19];
  const float* fc2_w   = (const float*)d_in[20];
  const float* fc2_b   = (const float*)d_in[21];
  const float* fc2_lw  = (const float*)d_in[22];
  const float* fc2_lb  = (const float*)d_in[23];

  // ---- lifetime-overlapped workspace layout (bytes) ----
  const size_t SZ_W      = 2u*4194304u*2u;                 // 16.78 MB (2x max weight)
  const size_t SZ_ARENA1 = 2u*(size_t)MP*HIDC*2u;          // 54.53 MB (qkv pair -> h pair)
  const size_t SZ_VT     = (size_t)64*64*SLEN*2u;          //  7.34 MB
  const size_t SZ_ARENA2 = 2u*SZ_VT;                       // 14.68 MB (vT pair -> x3 pair)
  const size_t SZ_ARENA3 = 2u*(size_t)MP*DIMC*2u;          // 13.63 MB (x1 pair -> o pair)
  const size_t SZ_X2     = (size_t)MP*DIMC*4u;             // 13.63 MB each
  const size_t NEEDED = SZ_W + SZ_ARENA1 + SZ_ARENA2 + SZ_ARENA3 + 2u*SZ_X2 + 4096u;
  if (ws_size < NEEDED) return;   // diagnosable failure instead of a fault

  char* base = (char*)d_ws;
  size_t off = 0;
  auto ab = [&](size_t bytes)->char*{
    char* p = base + off;
    off += bytes; off = (off + 255) & ~(size_t)255;
    return p;
  };
  char* Wslot  = ab(SZ_W);
  char* arena1 = ab(SZ_ARENA1);
  char* arena2 = ab(SZ_ARENA2);
  char* arena3 = ab(SZ_ARENA3);
  float* x2  = (float*)ab(SZ_X2);
  float* x2j = (float*)ab(SZ_X2);

  u16* wbuf  = (u16*)Wslot;
  u16* wjbuf = wbuf + 4194304;            // element offset (max weight elems)
  u16* qkvb  = (u16*)arena1;
  u16* qkvjb = qkvb + (size_t)MP*H3C;
  u16* hb    = (u16*)arena1;              // after attention: reuse for fc1 out
  u16* hjb   = hb + (size_t)MP*HIDC;
  u16* vT    = (u16*)arena2;
  u16* vjT   = vT + (size_t)64*64*SLEN;
  u16* x3b   = (u16*)arena2;              // after attention: reuse for ln2 out
  u16* x3jb  = x3b + (size_t)MP*DIMC;
  u16* x1b   = (u16*)arena3;
  u16* x1jb  = x1b + (size_t)MP*DIMC;
  u16* ob    = (u16*)arena3;              // after qkv gemm: reuse for attn out
  u16* ojb   = ob + (size_t)MP*DIMC;

  auto cvt2 = [&](const float* s0, u16* d0, int n0,
                  const float* s1, u16* d1, int n1){
    cvt2_k<<<dim3((n0 + n1 + 1023)/1024), 256, 0, stream>>>(s0, d0, n0, s1, d1, n1);
  };

  // LN1
  ln_jvp_k<<<dim3(MP), 256, 0, stream>>>(input, inputj, n1_w, n1_b, n1_lw, n1_lb,
                                         x1b, x1jb);
  // QKV (no bias) — w64 kernel (48x13 = 624 blocks, 2 blk/CU)
  cvt2(qkv_w, wbuf, H3C*DIMC, qkv_lw, wjbuf, H3C*DIMC);
  gemm_jvp_w64_k<0><<<dim3(H3C/64, MP/256), 256, 0, stream>>>(
      x1b, x1jb, DIMC, wbuf, wjbuf, DIMC, nullptr, nullptr,
      qkvb, qkvjb, H3C);
  // V transpose (all 64 head-batches)
  transpose_v_k<<<dim3(14, 64), 256, 0, stream>>>(qkvb, qkvjb, vT, vjT);
  // fused flash JVP attention: one launch, writes ob/ojb (aliases x1 arena)
  flash_attn_jvp_k<<<dim3(7, 64), 256, 0, stream>>>(qkvb, qkvjb, vT, vjT, ob, ojb);
  // proj + residual(input) -> x2 fp32 — 128^2 2-buf kernel (208 blocks)
  cvt2(proj_w, wbuf, DIMC*DIMC, proj_lw, wjbuf, DIMC*DIMC);
  gemm_jvp_k<1><<<dim3(DIMC/128, MP/128), 256, 0, stream>>>(
      ob, ojb, DIMC, wbuf, wjbuf, DIMC, proj_b, proj_lb, input, inputj,
      x2, x2j, DIMC, MREAL);
  // LN2
  ln_jvp_k<<<dim3(MP), 256, 0, stream>>>(x2, x2j, n2_w, n2_b, n2_lw, n2_lb,
                                         x3b, x3jb);
  // FC1 + GELU-JVP — w64 kernel (64x13 = 832 blocks, 2 blk/CU)
  cvt2(fc1_w, wbuf, HIDC*DIMC, fc1_lw, wjbuf, HIDC*DIMC);
  gemm_jvp_w64_k<2><<<dim3(HIDC/64, MP/256), 256, 0, stream>>>(
      x3b, x3jb, DIMC, wbuf, wjbuf, DIMC, fc1_b, fc1_lb,
      hb, hjb, HIDC);
  // FC2 + residual(x2) -> d_out — 128^2 2-buf kernel (208 blocks)
  cvt2(fc2_w, wbuf, DIMC*HIDC, fc2_lw, wjbuf, DIMC*HIDC);
  float* out0 = (float*)d_out;
  float* out1 = out0 + (size_t)MREAL*DIMC;
  gemm_jvp_k<1><<<dim3(DIMC/128, MP/128), 256, 0, stream>>>(
      hb, hjb, HIDC, wbuf, wjbuf, HIDC, fc2_b, fc2_lb, x2, x2j,
      out0, out1, DIMC, MREAL);
}

// Round 18
// 517.271 us; speedup vs baseline: 1.1388x; 1.1388x over previous
//
#include <hip/hip_runtime.h>
#include <hip/hip_bf16.h>

typedef unsigned short u16;
typedef unsigned int   u32;

#define MP     3328          // padded token rows (26*128 = 13*256)
#define MREAL  3140          // B*N = 4*785
#define DIMC   1024
#define H3C    3072
#define HIDC   4096
#define NKV    785
#define SLEN   896           // padded V^T row length (7*128)

typedef __bf16 bf16x8 __attribute__((ext_vector_type(8)));
typedef float  f32x4  __attribute__((ext_vector_type(4)));

#define MFMA(d,a,b) (d) = __builtin_amdgcn_mfma_f32_16x16x32_bf16((a),(b),(d),0,0,0)

__device__ __forceinline__ u16 f2bf(float f){
  u32 u = __builtin_bit_cast(u32, f);
  return (u16)((u + 0x7fffu + ((u >> 16) & 1u)) >> 16);
}
__device__ __forceinline__ float bf2f(u16 h){
  return __builtin_bit_cast(float, (u32)h << 16);
}
__device__ __forceinline__ void gload16(const u16* g, u16* l){
  __builtin_amdgcn_global_load_lds(
      (const __attribute__((address_space(1))) void*)g,
      (__attribute__((address_space(3))) void*)l, 16, 0, 0);
}
__device__ __forceinline__ float wsum(float v){
  #pragma unroll
  for (int o = 32; o >= 1; o >>= 1) v += __shfl_xor(v, o);
  return v;
}

// ---------------- fp32 -> bf16 weight conversion (pairs fused) --------------
__global__ __launch_bounds__(256) void cvt2_k(
    const float* __restrict__ in0, u16* __restrict__ out0, int n0,
    const float* __restrict__ in1, u16* __restrict__ out1, int n1)
{
  int i = (blockIdx.x * 256 + threadIdx.x) * 4;
  const float* src; u16* dst;
  if (i < n0){ src = in0 + i; dst = out0 + i; }
  else { int j = i - n0; if (j >= n1) return; src = in1 + j; dst = out1 + j; }
  float4 v = *(const float4*)src;
  ushort4 o4;
  o4.x = f2bf(v.x); o4.y = f2bf(v.y); o4.z = f2bf(v.z); o4.w = f2bf(v.w);
  *(ushort4*)dst = o4;
}

// ---------------- LayerNorm + JVP (fp32 in -> bf16 out, zero pad rows) -----
__global__ __launch_bounds__(256) void ln_jvp_k(
    const float* __restrict__ x, const float* __restrict__ xj,
    const float* __restrict__ w, const float* __restrict__ b,
    const float* __restrict__ lw, const float* __restrict__ lb,
    u16* __restrict__ out, u16* __restrict__ outj)
{
  const int row = blockIdx.x, t = threadIdx.x;
  const size_t ro = (size_t)row * DIMC;
  if (row >= MREAL){
    for (int i = t; i < DIMC; i += 256){ out[ro+i] = 0; outj[ro+i] = 0; }
    return;
  }
  const float4 v  = ((const float4*)(x  + ro))[t];
  const float4 vj = ((const float4*)(xj + ro))[t];
  float sx  = v.x+v.y+v.z+v.w;
  float sxx = v.x*v.x+v.y*v.y+v.z*v.z+v.w*v.w;
  float sj  = vj.x+vj.y+vj.z+vj.w;
  float sxj = v.x*vj.x+v.y*vj.y+v.z*vj.z+v.w*vj.w;
  __shared__ __attribute__((aligned(64))) float red[4][4];
  sx = wsum(sx); sxx = wsum(sxx); sj = wsum(sj); sxj = wsum(sxj);
  const int wid = t>>6, lane = t&63;
  if (lane == 0){ red[wid][0]=sx; red[wid][1]=sxx; red[wid][2]=sj; red[wid][3]=sxj; }
  __syncthreads();
  sx  = red[0][0]+red[1][0]+red[2][0]+red[3][0];
  sxx = red[0][1]+red[1][1]+red[2][1]+red[3][1];
  sj  = red[0][2]+red[1][2]+red[2][2]+red[3][2];
  sxj = red[0][3]+red[1][3]+red[2][3]+red[3][3];
  const float inv  = 1.0f/1024.0f;
  const float mean = sx*inv, meanj = sj*inv;
  const float var  = sxx*inv - mean*mean;
  const float cov  = sxj*inv - mean*meanj;       // mean(xc*xjc)
  const float rstd = rsqrtf(var + 1e-5f);
  const float r3   = rstd*rstd*rstd;
  const float4 wv  = ((const float4*)w)[t];
  const float4 bv  = ((const float4*)b)[t];
  const float4 lwv = ((const float4*)lw)[t];
  const float4 lbv = ((const float4*)lb)[t];
  const float xs[4]  = {v.x,v.y,v.z,v.w},   xjs[4] = {vj.x,vj.y,vj.z,vj.w};
  const float wss[4] = {wv.x,wv.y,wv.z,wv.w}, bs[4] = {bv.x,bv.y,bv.z,bv.w};
  const float lws[4] = {lwv.x,lwv.y,lwv.z,lwv.w}, lbs[4] = {lbv.x,lbv.y,lbv.z,lbv.w};
  const int i0 = t*4;
  #pragma unroll
  for (int e = 0; e < 4; e++){
    const float xc = xs[e]-mean, xjc = xjs[e]-meanj;
    const float xhat = xc*rstd;
    const float cc = xjc*rstd - xc*cov*r3;       // == (1/std^2)(a - bterm)
    out [ro+i0+e] = f2bf(xhat*wss[e] + bs[e]);
    outj[ro+i0+e] = f2bf(xhat*lws[e] + lbs[e] + cc*wss[e]);
  }
}

// ============ WIDE JVP GEMM: BM=256 BN=128 BK=32, 8 waves, depth-2 ==========
// Triple-buffered LDS (3 x 48KB), counted s_waitcnt vmcnt(6). XOR-swizzle
// involution (byte ^= ((byte>>7)&7)<<4). XCD-aware block swizzle.
// Best measured for K=1024/wide-N (qkv, fc1): BM=256 halves per-M-stripe
// B re-stream (r15); BN=64 variant starved the B-side (r17).
template<int EPI>
__global__ __launch_bounds__(512, 1) void gemm_jvp_wide_k(
    const u16* __restrict__ A, const u16* __restrict__ Aj, int lda,
    const u16* __restrict__ B, const u16* __restrict__ Bj, int K,
    const float* __restrict__ bias, const float* __restrict__ biasj,
    void* __restrict__ Yv, void* __restrict__ Yjv, int ldy)
{
  __shared__ __attribute__((aligned(128))) u16 lds[3][24576];
  const int tid = threadIdx.x, wid = tid>>6, lane = tid&63;
  const int l4 = lane>>4, l15 = lane&15;
  const int ord = blockIdx.y * gridDim.x + blockIdx.x;
  const int cpx = (gridDim.x * gridDim.y) >> 3;
  const int nbk = (ord & 7) * cpx + (ord >> 3);
  const int m0 = (nbk / gridDim.x) * 256;
  const int n0 = (nbk % gridDim.x) * 128;
  f32x4 accY[4][4], accJ[4][4];
  #pragma unroll
  for (int i = 0; i < 4; i++)
    #pragma unroll
    for (int j = 0; j < 4; j++){
      accY[i][j] = (f32x4){0.f,0.f,0.f,0.f};
      accJ[i][j] = (f32x4){0.f,0.f,0.f,0.f};
    }
  const int boA0 = tid*16,        boA1 = (512+tid)*16;
  const int sbA0 = boA0 ^ (((boA0>>7)&7)<<4);
  const int sbA1 = boA1 ^ (((boA1>>7)&7)<<4);
  const int rA0 = sbA0>>6, cA0 = (sbA0&63)>>1;
  const int rA1 = sbA1>>6, cA1 = (sbA1&63)>>1;
  const int boB = tid*16;
  const int sbB = boB ^ (((boB>>7)&7)<<4);
  const int rB = sbB>>6, cB = (sbB&63)>>1;
  const u16* srcA0  = A  + (size_t)(m0+rA0)*lda + cA0;
  const u16* srcA1  = A  + (size_t)(m0+rA1)*lda + cA1;
  const u16* srcAj0 = Aj + (size_t)(m0+rA0)*lda + cA0;
  const u16* srcAj1 = Aj + (size_t)(m0+rA1)*lda + cA1;
  const u16* srcB   = B  + (size_t)(n0+rB)*K + cB;
  const u16* srcBj  = Bj + (size_t)(n0+rB)*K + cB;
  const int dA0 = tid*8, dA1 = (512+tid)*8, dB = tid*8;
  const int wr = wid>>1, wc = wid&1;
  int aoff[4], boff[4];
  #pragma unroll
  for (int i = 0; i < 4; i++){
    int ab_ = (wr*64 + i*16 + l15)*64 + l4*16;
    aoff[i] = ab_ ^ (((ab_>>7)&7)<<4);
    int bb_ = (wc*64 + i*16 + l15)*64 + l4*16;
    boff[i] = bb_ ^ (((bb_>>7)&7)<<4);
  }
  auto STAGE = [&](int buf, int t){
    const int k0 = t<<5;
    u16* Lb = &lds[buf][0];
    gload16(srcA0 +k0, Lb + dA0);
    gload16(srcA1 +k0, Lb + dA1);
    gload16(srcAj0+k0, Lb + 8192 + dA0);
    gload16(srcAj1+k0, Lb + 8192 + dA1);
    gload16(srcB  +k0, Lb + 16384 + dB);
    gload16(srcBj +k0, Lb + 20480 + dB);
  };
  const int nt = K >> 5;
  STAGE(0, 0);
  STAGE(1, 1);
  for (int t = 0; t < nt; t++){
    if (t + 1 < nt) asm volatile("s_waitcnt vmcnt(6)" ::: "memory");
    else            asm volatile("s_waitcnt vmcnt(0)" ::: "memory");
    __builtin_amdgcn_s_barrier();
    if (t + 2 < nt) STAGE((t+2)%3, t+2);
    const char* Lb = (const char*)&lds[t%3][0];
    bf16x8 af[4], ajf[4], bbf[4], bjf[4];
    #pragma unroll
    for (int i = 0; i < 4; i++){
      af[i]  = *(const bf16x8*)(Lb + aoff[i]);
      ajf[i] = *(const bf16x8*)(Lb + 16384 + aoff[i]);
      bbf[i] = *(const bf16x8*)(Lb + 32768 + boff[i]);
      bjf[i] = *(const bf16x8*)(Lb + 40960 + boff[i]);
    }
    __builtin_amdgcn_s_setprio(1);
    #pragma unroll
    for (int i = 0; i < 4; i++)
      #pragma unroll
      for (int j = 0; j < 4; j++){
        MFMA(accY[i][j], af[i],  bbf[j]);
        MFMA(accJ[i][j], ajf[i], bbf[j]);
        MFMA(accJ[i][j], af[i],  bjf[j]);
      }
    __builtin_amdgcn_s_setprio(0);
  }
  const int mb = m0 + wr*64 + (l4<<2);
  const int nb = n0 + wc*64 + l15;
  #pragma unroll
  for (int i = 0; i < 4; i++)
    #pragma unroll
    for (int j = 0; j < 4; j++)
      #pragma unroll
      for (int r = 0; r < 4; r++){
        const int m = mb + i*16 + r, n = nb + j*16;
        float y = accY[i][j][r], yj = accJ[i][j][r];
        if (EPI == 0){
          ((u16*)Yv )[(size_t)m*ldy+n] = f2bf(y);
          ((u16*)Yjv)[(size_t)m*ldy+n] = f2bf(yj);
        } else {
          y  += bias[n];
          yj += biasj[n];
          const float ge  = 0.5f*y*(1.0f + erff(y*0.70710678118654752f));
          const float pdf = __expf(-0.5f*y*y)*0.3989422804014327f;
          const float gj  = yj*(ge/(y + 1e-8f) + y*pdf);
          ((u16*)Yv )[(size_t)m*ldy+n] = f2bf(ge);
          ((u16*)Yjv)[(size_t)m*ldy+n] = f2bf(gj);
        }
      }
}

// ---------------- 128x128 JVP GEMM, 2-buffer counted-vmcnt ------------------
// Proven best for K=4096/narrow-N (fc2) and proj: 2-buffer LDS (64KB) ->
// 2 blocks/CU (8 waves TLP), counted vmcnt(8), post-compute barrier guards
// WAR on buffer reuse. XOR-swizzle + XCD swizzle.
template<int EPI>
__global__ __launch_bounds__(256) void gemm_jvp_k(
    const u16* __restrict__ A, const u16* __restrict__ Aj, int lda,
    const u16* __restrict__ B, const u16* __restrict__ Bj, int K,
    const float* __restrict__ bias, const float* __restrict__ biasj,
    const float* __restrict__ res, const float* __restrict__ resj,
    void* __restrict__ Yv, void* __restrict__ Yjv, int ldy, int mwrite)
{
  // [buf][tile: A,Aj,B,Bj][128x32 bf16] = 64 KB total
  __shared__ __attribute__((aligned(128))) u16 lds[2][4][128*32];
  const int tid = threadIdx.x, wid = tid>>6, lane = tid&63;
  const int ord = blockIdx.y * gridDim.x + blockIdx.x;
  const int cpx = (gridDim.x * gridDim.y) >> 3;
  const int nbk = (ord & 7) * cpx + (ord >> 3);
  const int m0 = (nbk / gridDim.x) * 128;
  const int n0 = (nbk % gridDim.x) * 128;
  f32x4 accY[4][4], accJ[4][4];
  #pragma unroll
  for (int i = 0; i < 4; i++)
    #pragma unroll
    for (int j = 0; j < 4; j++){
      accY[i][j] = (f32x4){0.f,0.f,0.f,0.f};
      accJ[i][j] = (f32x4){0.f,0.f,0.f,0.f};
    }
  const int bo0 = wid*1024 + lane*16;     // staging byte offset, round 0
  const int bo1 = bo0 + 4096;             // round 1
  const int sb0 = bo0 ^ (((bo0>>7)&7)<<4);
  const int sb1 = bo1 ^ (((bo1>>7)&7)<<4);
  const int r0 = sb0>>6, c0 = (sb0&63)>>1;
  const int r1 = sb1>>6, c1 = (sb1&63)>>1;
  const u16* A0  = A  + (size_t)(m0+r0)*lda + c0;
  const u16* A1  = A  + (size_t)(m0+r1)*lda + c1;
  const u16* Aj0 = Aj + (size_t)(m0+r0)*lda + c0;
  const u16* Aj1 = Aj + (size_t)(m0+r1)*lda + c1;
  const u16* B0  = B  + (size_t)(n0+r0)*K + c0;
  const u16* B1  = B  + (size_t)(n0+r1)*K + c1;
  const u16* Bj0 = Bj + (size_t)(n0+r0)*K + c0;
  const u16* Bj1 = Bj + (size_t)(n0+r1)*K + c1;
  const int kq = (lane>>4)<<3;
  const int ar = (wid>>1)*64 + (lane&15);
  const int bc = (wid&1)*64 + (lane&15);
  int aoff[4], boff[4];
  #pragma unroll
  for (int i = 0; i < 4; i++){
    int ab_ = (ar+i*16)*64 + (kq<<1);
    aoff[i] = ab_ ^ (((ab_>>7)&7)<<4);
    int bb_ = (bc+i*16)*64 + (kq<<1);
    boff[i] = bb_ ^ (((bb_>>7)&7)<<4);
  }
  auto STAGE = [&](int buf, int t){
    const int k0 = t<<5;
    u16* p0 = &lds[buf][0][0];
    gload16(A0 +k0, p0+(bo0>>1)); gload16(A1 +k0, p0+(bo1>>1));
    u16* p1 = &lds[buf][1][0];
    gload16(Aj0+k0, p1+(bo0>>1)); gload16(Aj1+k0, p1+(bo1>>1));
    u16* p2 = &lds[buf][2][0];
    gload16(B0 +k0, p2+(bo0>>1)); gload16(B1 +k0, p2+(bo1>>1));
    u16* p3 = &lds[buf][3][0];
    gload16(Bj0+k0, p3+(bo0>>1)); gload16(Bj1+k0, p3+(bo1>>1));
  };
  const int nt = K >> 5;
  STAGE(0, 0);
  STAGE(1, 1);
  for (int t = 0; t < nt; t++){
    if (t + 1 < nt) asm volatile("s_waitcnt vmcnt(8)" ::: "memory");
    else            asm volatile("s_waitcnt vmcnt(0)" ::: "memory");
    __builtin_amdgcn_s_barrier();
    const char* lAb  = (const char*)&lds[t&1][0][0];
    const char* lAjb = (const char*)&lds[t&1][1][0];
    const char* lBb  = (const char*)&lds[t&1][2][0];
    const char* lBjb = (const char*)&lds[t&1][3][0];
    bf16x8 af[4], ajf[4], bbf[4], bjf[4];
    #pragma unroll
    for (int i = 0; i < 4; i++){
      af[i]  = *(const bf16x8*)(lAb  + aoff[i]);
      ajf[i] = *(const bf16x8*)(lAjb + aoff[i]);
      bbf[i] = *(const bf16x8*)(lBb  + boff[i]);
      bjf[i] = *(const bf16x8*)(lBjb + boff[i]);
    }
    __builtin_amdgcn_s_setprio(1);
    #pragma unroll
    for (int i = 0; i < 4; i++)
      #pragma unroll
      for (int j = 0; j < 4; j++){
        MFMA(accY[i][j], af[i],  bbf[j]);
        MFMA(accJ[i][j], ajf[i], bbf[j]);
        MFMA(accJ[i][j], af[i],  bjf[j]);
      }
    __builtin_amdgcn_s_setprio(0);
    __builtin_amdgcn_s_barrier();          // all waves done reading buf[t&1]
    if (t + 2 < nt) STAGE(t&1, t+2);       // refill; flies across next wait
  }
  const int mb = m0 + (wid>>1)*64 + ((lane>>4)<<2);
  const int nb = n0 + (wid&1)*64 + (lane&15);
  #pragma unroll
  for (int i = 0; i < 4; i++)
    #pragma unroll
    for (int j = 0; j < 4; j++)
      #pragma unroll
      for (int r = 0; r < 4; r++){
        const int m = mb + i*16 + r, n = nb + j*16;
        float y = accY[i][j][r], yj = accJ[i][j][r];
        if (EPI == 0){
          ((u16*)Yv )[(size_t)m*ldy+n] = f2bf(y);
          ((u16*)Yjv)[(size_t)m*ldy+n] = f2bf(yj);
        } else if (EPI == 1){
          if (m < mwrite){
            y  += bias[n]  + res [(size_t)m*ldy+n];
            yj += biasj[n] + resj[(size_t)m*ldy+n];
            ((float*)Yv )[(size_t)m*ldy+n] = y;
            ((float*)Yjv)[(size_t)m*ldy+n] = yj;
          }
        } else {
          y  += bias[n];
          yj += biasj[n];
          const float ge  = 0.5f*y*(1.0f + erff(y*0.70710678118654752f));
          const float pdf = __expf(-0.5f*y*y)*0.3989422804014327f;
          const float gj  = yj*(ge/(y + 1e-8f) + y*pdf);
          ((u16*)Yv )[(size_t)m*ldy+n] = f2bf(ge);
          ((u16*)Yjv)[(size_t)m*ldy+n] = f2bf(gj);
        }
      }
}

// ---------------- V transpose: vT[bh][d][kv] (zero-padded kv>=785) ----------
__global__ __launch_bounds__(256) void transpose_v_k(
    const u16* __restrict__ qkvb, const u16* __restrict__ qkvjb,
    u16* __restrict__ vT, u16* __restrict__ vjT)
{
  __shared__ __attribute__((aligned(64))) u16 tl[64][80];
  __shared__ __attribute__((aligned(64))) u16 tlj[64][80];
  const int kt = blockIdx.x, bh = blockIdx.y;
  const int b = bh>>4, h = bh&15;
  const int t = threadIdx.x;
  const int kv = t>>2, dd = (t&3)*16;
  const int kvg = kt*64 + kv;
  if (kvg < NKV){
    const u16* s0 = qkvb  + (size_t)(b*NKV+kvg)*H3C + 2048 + h*64 + dd;
    const u16* s1 = qkvjb + (size_t)(b*NKV+kvg)*H3C + 2048 + h*64 + dd;
    *(uint4*)&tl [kv][dd]   = *(const uint4*)s0;
    *(uint4*)&tl [kv][dd+8] = *(const uint4*)(s0+8);
    *(uint4*)&tlj[kv][dd]   = *(const uint4*)s1;
    *(uint4*)&tlj[kv][dd+8] = *(const uint4*)(s1+8);
  } else {
    uint4 z = {0,0,0,0};
    *(uint4*)&tl [kv][dd] = z; *(uint4*)&tl [kv][dd+8] = z;
    *(uint4*)&tlj[kv][dd] = z; *(uint4*)&tlj[kv][dd+8] = z;
  }
  __syncthreads();
  const int d = t>>2, kc = (t&3)*16;
  u16* d0 = vT  + ((size_t)bh*64 + d)*SLEN + kt*64 + kc;
  u16* d1 = vjT + ((size_t)bh*64 + d)*SLEN + kt*64 + kc;
  #pragma unroll
  for (int e = 0; e < 16; e++){ d0[e] = tl[kc+e][d]; d1[e] = tlj[kc+e][d]; }
}

// ---------------- fused flash-style JVP attention ---------------------------
// K/Kj double-buffered, V single-buffered; counted vmcnt(4); l/g reductions
// deferred to epilogue; defer-max (skip rescale unless row max grew > 4).
// LDS = 80 KB -> 2 blocks/CU.
__global__ __launch_bounds__(256) void flash_attn_jvp_k(
    const u16* __restrict__ qkvb, const u16* __restrict__ qkvjb,
    const u16* __restrict__ vT, const u16* __restrict__ vjT,
    u16* __restrict__ o, u16* __restrict__ oj)
{
  __shared__ __attribute__((aligned(128))) u16 lK  [2][64*64];
  __shared__ __attribute__((aligned(128))) u16 lKj [2][64*64];
  __shared__ __attribute__((aligned(128))) u16 lvT [64*64];
  __shared__ __attribute__((aligned(128))) u16 lvjT[64*64];
  __shared__ __attribute__((aligned(128))) u16 pl  [128*64];
  __shared__ __attribute__((aligned(128))) u16 pdl [128*64];
  const int tid = threadIdx.x, wid = tid>>6, lane = tid&63;
  const int l4 = lane>>4, l15 = lane&15;
  const int qt = blockIdx.x, bh = blockIdx.y, b = bh>>4, h = bh&15;

  bf16x8 qf[2][2], qjf[2][2];
  {
    const size_t qrb = (size_t)b*NKV + qt*128 + wid*32;
    #pragma unroll
    for (int i = 0; i < 2; i++){
      const size_t ro = (qrb + i*16 + l15)*H3C + h*64;
      #pragma unroll
      for (int ks = 0; ks < 2; ks++){
        qf [i][ks] = *(const bf16x8*)(qkvb  + ro + ks*32 + l4*8);
        qjf[i][ks] = *(const bf16x8*)(qkvjb + ro + ks*32 + l4*8);
      }
    }
  }
  float m_st[2][4], l_pt[2][4], g_pt[2][4];
  f32x4 PO[2][4], PTJ[2][4];
  #pragma unroll
  for (int i = 0; i < 2; i++)
    #pragma unroll
    for (int r = 0; r < 4; r++){
      m_st[i][r] = -1e30f; l_pt[i][r] = 0.f; g_pt[i][r] = 0.f;
    }
  #pragma unroll
  for (int i = 0; i < 2; i++)
    #pragma unroll
    for (int j = 0; j < 4; j++){
      PO[i][j] = (f32x4){0.f,0.f,0.f,0.f};
      PTJ[i][j] = (f32x4){0.f,0.f,0.f,0.f};
    }
  char* plb  = (char*)pl;
  char* pdlb = (char*)pdl;
  const char* lvTb  = (const char*)lvT;
  const char* lvjTb = (const char*)lvjT;

  const int g0 = tid, g1 = 256 + tid;
  const int row0 = g0>>3, cs0 = (g0&7) ^ (row0&7);
  const int row1 = g1>>3, cs1 = (g1&7) ^ (row1&7);
  auto stageK = [&](int buf, int t){
    const size_t k0 = (size_t)(b*NKV + t*64 + row0)*H3C + 1024 + h*64 + cs0*8;
    const size_t k1 = (size_t)(b*NKV + t*64 + row1)*H3C + 1024 + h*64 + cs1*8;
    gload16(qkvb  + k0, &lK [buf][0] + g0*8);
    gload16(qkvjb + k0, &lKj[buf][0] + g0*8);
    gload16(qkvb  + k1, &lK [buf][0] + g1*8);
    gload16(qkvjb + k1, &lKj[buf][0] + g1*8);
  };
  auto stageV = [&](int t){
    const size_t v0 = ((size_t)bh*64 + row0)*SLEN + t*64 + cs0*8;
    const size_t v1 = ((size_t)bh*64 + row1)*SLEN + t*64 + cs1*8;
    gload16(vT  + v0, lvT  + g0*8);
    gload16(vjT + v0, lvjT + g0*8);
    gload16(vT  + v1, lvT  + g1*8);
    gload16(vjT + v1, lvjT + g1*8);
  };

  stageK(0, 0);
  stageV(0);
  for (int t = 0; t < 13; t++){
    asm volatile("s_waitcnt vmcnt(4)" ::: "memory");   // K(t) complete
    __builtin_amdgcn_s_barrier();
    const char* lKb  = (const char*)&lK [t&1][0];
    const char* lKjb = (const char*)&lKj[t&1][0];

    #pragma unroll
    for (int i = 0; i < 2; i++){
      f32x4 s[4], dm[4];
      #pragma unroll
      for (int j = 0; j < 4; j++){
        s[j] = (f32x4){0.f,0.f,0.f,0.f};
        dm[j] = (f32x4){0.f,0.f,0.f,0.f};
      }
      #pragma unroll
      for (int ks = 0; ks < 2; ks++){
        #pragma unroll
        for (int j = 0; j < 4; j++){
          const int row = j*16 + l15;
          const int byt = (row*128 + ks*64 + l4*16) ^ ((row&7)<<4);
          const bf16x8 kf  = *(const bf16x8*)(lKb  + byt);
          const bf16x8 kjf = *(const bf16x8*)(lKjb + byt);
          MFMA(s[j],  qf[i][ks],  kf);
          MFMA(dm[j], qjf[i][ks], kf);
          MFMA(dm[j], qf[i][ks],  kjf);
        }
      }
      float tm[4] = {-1e30f,-1e30f,-1e30f,-1e30f};
      #pragma unroll
      for (int j = 0; j < 4; j++){
        const int colg = t*64 + j*16 + l15;
        #pragma unroll
        for (int r = 0; r < 4; r++){
          float sv = s[j][r]*0.125f;
          if (colg >= NKV) sv = -1e30f;
          s[j][r] = sv;
          dm[j][r] *= 0.125f;
          tm[r] = fmaxf(tm[r], sv);
        }
      }
      float vmax[4];
      bool need = false;
      #pragma unroll
      for (int r = 0; r < 4; r++){
        float v = tm[r];
        v = fmaxf(v, __shfl_xor(v, 1));
        v = fmaxf(v, __shfl_xor(v, 2));
        v = fmaxf(v, __shfl_xor(v, 4));
        v = fmaxf(v, __shfl_xor(v, 8));
        vmax[r] = v;
        need = need || (v > m_st[i][r] + 4.0f);
      }
      if (__any(need)){
        #pragma unroll
        for (int r = 0; r < 4; r++){
          const float nm = fmaxf(m_st[i][r], vmax[r]);
          const float sc = __expf(m_st[i][r] - nm);
          m_st[i][r] = nm;
          l_pt[i][r] *= sc;
          g_pt[i][r] *= sc;
          #pragma unroll
          for (int j = 0; j < 4; j++){ PO[i][j][r] *= sc; PTJ[i][j][r] *= sc; }
        }
      }
      #pragma unroll
      for (int j = 0; j < 4; j++){
        const int col = j*16 + l15;
        #pragma unroll
        for (int r = 0; r < 4; r++){
          const float p  = __expf(s[j][r] - m_st[i][r]);
          const float pd = p * dm[j][r];
          l_pt[i][r] += p;
          g_pt[i][r] += pd;
          const int row = wid*32 + i*16 + l4*4 + r;
          const int byt = (row*128 + col*2) ^ ((row&7)<<4);
          *(u16*)(plb  + byt) = f2bf(p);
          *(u16*)(pdlb + byt) = f2bf(pd);
        }
      }
    }

    if (t + 1 < 13) stageK((t+1)&1, t+1);
    if (t + 1 < 13) asm volatile("s_waitcnt vmcnt(4)" ::: "memory");
    else            asm volatile("s_waitcnt vmcnt(0)" ::: "memory");
    __builtin_amdgcn_s_barrier();

    #pragma unroll
    for (int ks = 0; ks < 2; ks++){
      bf16x8 pa[2], pda[2];
      #pragma unroll
      for (int i = 0; i < 2; i++){
        const int row = wid*32 + i*16 + l15;
        const int byt = (row*128 + ks*64 + l4*16) ^ ((row&7)<<4);
        pa[i]  = *(const bf16x8*)(plb  + byt);
        pda[i] = *(const bf16x8*)(pdlb + byt);
      }
      #pragma unroll
      for (int j = 0; j < 4; j++){
        const int row = j*16 + l15;
        const int byt = (row*128 + ks*64 + l4*16) ^ ((row&7)<<4);
        const bf16x8 vb  = *(const bf16x8*)(lvTb  + byt);
        const bf16x8 vjb = *(const bf16x8*)(lvjTb + byt);
        #pragma unroll
        for (int i = 0; i < 2; i++){
          MFMA(PO[i][j],  pa[i],  vb);
          MFMA(PTJ[i][j], pda[i], vb);
          MFMA(PTJ[i][j], pa[i],  vjb);
        }
      }
    }
    __builtin_amdgcn_s_barrier();
    if (t + 1 < 13) stageV(t+1);
  }

  #pragma unroll
  for (int i = 0; i < 2; i++)
    #pragma unroll
    for (int r = 0; r < 4; r++){
      float lv = l_pt[i][r], gv = g_pt[i][r];
      lv += __shfl_xor(lv, 1); gv += __shfl_xor(gv, 1);
      lv += __shfl_xor(lv, 2); gv += __shfl_xor(gv, 2);
      lv += __shfl_xor(lv, 4); gv += __shfl_xor(gv, 4);
      lv += __shfl_xor(lv, 8); gv += __shfl_xor(gv, 8);
      const int ql = qt*128 + wid*32 + i*16 + l4*4 + r;
      if (ql < NKV){
        const float rl = 1.0f / lv;
        const float gg = gv * rl;
        #pragma unroll
        for (int j = 0; j < 4; j++){
          const size_t oo = ((size_t)b*NKV + ql)*DIMC + h*64 + j*16 + l15;
          const float po = PO[i][j][r] * rl;
          o [oo] = f2bf(po);
          oj[oo] = f2bf(PTJ[i][j][r]*rl - gg*po);
        }
      }
    }
}

// ---------------------------------------------------------------------------
extern "C" void kernel_launch(void* const* d_in, const int* in_sizes, int n_in,
                              void* d_out, int out_size, void* d_ws, size_t ws_size,
                              hipStream_t stream)
{
  (void)in_sizes; (void)n_in; (void)out_size;
  const float* input   = (const float*)d_in[0];
  const float* inputj  = (const float*)d_in[1];
  const float* n1_w    = (const float*)d_in[2];
  const float* n1_b    = (const float*)d_in[3];
  const float* n1_lw   = (const float*)d_in[4];
  const float* n1_lb   = (const float*)d_in[5];
  const float* qkv_w   = (const float*)d_in[6];
  const float* qkv_lw  = (const float*)d_in[7];
  const float* proj_w  = (const float*)d_in[8];
  const float* proj_b  = (const float*)d_in[9];
  const float* proj_lw = (const float*)d_in[10];
  const float* proj_lb = (const float*)d_in[11];
  const float* n2_w    = (const float*)d_in[12];
  const float* n2_b    = (const float*)d_in[13];
  const float* n2_lw   = (const float*)d_in[14];
  const float* n2_lb   = (const float*)d_in[15];
  const float* fc1_w   = (const float*)d_in[16];
  const float* fc1_b   = (const float*)d_in[17];
  const float* fc1_lw  = (const float*)d_in[18];
  const float* fc1_lb  = (const float*)d_in[19];
  const float* fc2_w   = (const float*)d_in[20];
  const float* fc2_b   = (const float*)d_in[21];
  const float* fc2_lw  = (const float*)d_in[22];
  const float* fc2_lb  = (const float*)d_in[23];

  // ---- lifetime-overlapped workspace layout (bytes) ----
  const size_t SZ_W      = 2u*4194304u*2u;                 // 16.78 MB (2x max weight)
  const size_t SZ_ARENA1 = 2u*(size_t)MP*HIDC*2u;          // 54.53 MB (qkv pair -> h pair)
  const size_t SZ_VT     = (size_t)64*64*SLEN*2u;          //  7.34 MB
  const size_t SZ_ARENA2 = 2u*SZ_VT;                       // 14.68 MB (vT pair -> x3 pair)
  const size_t SZ_ARENA3 = 2u*(size_t)MP*DIMC*2u;          // 13.63 MB (x1 pair -> o pair)
  const size_t SZ_X2     = (size_t)MP*DIMC*4u;             // 13.63 MB each
  const size_t NEEDED = SZ_W + SZ_ARENA1 + SZ_ARENA2 + SZ_ARENA3 + 2u*SZ_X2 + 4096u;
  if (ws_size < NEEDED) return;   // diagnosable failure instead of a fault

  char* base = (char*)d_ws;
  size_t off = 0;
  auto ab = [&](size_t bytes)->char*{
    char* p = base + off;
    off += bytes; off = (off + 255) & ~(size_t)255;
    return p;
  };
  char* Wslot  = ab(SZ_W);
  char* arena1 = ab(SZ_ARENA1);
  char* arena2 = ab(SZ_ARENA2);
  char* arena3 = ab(SZ_ARENA3);
  float* x2  = (float*)ab(SZ_X2);
  float* x2j = (float*)ab(SZ_X2);

  u16* wbuf  = (u16*)Wslot;
  u16* wjbuf = wbuf + 4194304;            // element offset (max weight elems)
  u16* qkvb  = (u16*)arena1;
  u16* qkvjb = qkvb + (size_t)MP*H3C;
  u16* hb    = (u16*)arena1;              // after attention: reuse for fc1 out
  u16* hjb   = hb + (size_t)MP*HIDC;
  u16* vT    = (u16*)arena2;
  u16* vjT   = vT + (size_t)64*64*SLEN;
  u16* x3b   = (u16*)arena2;              // after attention: reuse for ln2 out
  u16* x3jb  = x3b + (size_t)MP*DIMC;
  u16* x1b   = (u16*)arena3;
  u16* x1jb  = x1b + (size_t)MP*DIMC;
  u16* ob    = (u16*)arena3;              // after qkv gemm: reuse for attn out
  u16* ojb   = ob + (size_t)MP*DIMC;

  auto cvt2 = [&](const float* s0, u16* d0, int n0,
                  const float* s1, u16* d1, int n1){
    cvt2_k<<<dim3((n0 + n1 + 1023)/1024), 256, 0, stream>>>(s0, d0, n0, s1, d1, n1);
  };

  // LN1
  ln_jvp_k<<<dim3(MP), 256, 0, stream>>>(input, inputj, n1_w, n1_b, n1_lw, n1_lb,
                                         x1b, x1jb);
  // QKV (no bias) — wide depth-2 kernel (24x13 = 312 blocks)
  cvt2(qkv_w, wbuf, H3C*DIMC, qkv_lw, wjbuf, H3C*DIMC);
  gemm_jvp_wide_k<0><<<dim3(H3C/128, MP/256), 512, 0, stream>>>(
      x1b, x1jb, DIMC, wbuf, wjbuf, DIMC, nullptr, nullptr,
      qkvb, qkvjb, H3C);
  // V transpose (all 64 head-batches)
  transpose_v_k<<<dim3(14, 64), 256, 0, stream>>>(qkvb, qkvjb, vT, vjT);
  // fused flash JVP attention: one launch, writes ob/ojb (aliases x1 arena)
  flash_attn_jvp_k<<<dim3(7, 64), 256, 0, stream>>>(qkvb, qkvjb, vT, vjT, ob, ojb);
  // proj + residual(input) -> x2 fp32 — 128^2 2-buf kernel (208 blocks)
  cvt2(proj_w, wbuf, DIMC*DIMC, proj_lw, wjbuf, DIMC*DIMC);
  gemm_jvp_k<1><<<dim3(DIMC/128, MP/128), 256, 0, stream>>>(
      ob, ojb, DIMC, wbuf, wjbuf, DIMC, proj_b, proj_lb, input, inputj,
      x2, x2j, DIMC, MREAL);
  // LN2
  ln_jvp_k<<<dim3(MP), 256, 0, stream>>>(x2, x2j, n2_w, n2_b, n2_lw, n2_lb,
                                         x3b, x3jb);
  // FC1 + GELU-JVP — wide depth-2 kernel (32x13 = 416 blocks)
  cvt2(fc1_w, wbuf, HIDC*DIMC, fc1_lw, wjbuf, HIDC*DIMC);
  gemm_jvp_wide_k<2><<<dim3(HIDC/128, MP/256), 512, 0, stream>>>(
      x3b, x3jb, DIMC, wbuf, wjbuf, DIMC, fc1_b, fc1_lb,
      hb, hjb, HIDC);
  // FC2 + residual(x2) -> d_out — 128^2 2-buf kernel (208 blocks)
  cvt2(fc2_w, wbuf, DIMC*HIDC, fc2_lw, wjbuf, DIMC*HIDC);
  float* out0 = (float*)d_out;
  float* out1 = out0 + (size_t)MREAL*DIMC;
  gemm_jvp_k<1><<<dim3(DIMC/128, MP/128), 256, 0, stream>>>(
      hb, hjb, HIDC, wbuf, wjbuf, HIDC, fc2_b, fc2_lb, x2, x2j,
      out0, out1, DIMC, MREAL);
}